// Round 5
// baseline (1587.436 us; speedup 1.0000x reference)
//
#include <hip/hip_runtime.h>

// PiecewiseLinearEmbedding: out[i,t,:] = cumsum(W, axis=1)[:, x[i,t]] + b
// R5: DIAGNOSTIC round. R4 kernel + a non-elidable dependent VALU chain
// (KCHAIN fma/iter) to inflate embed_main past the ~268 us top-5 cut so its
// own counters (WRITE_SIZE / FETCH_SIZE / LDS conflicts / timestamps) become
// visible. Output is bit-identical (guard branch never taken).
// embed_true ~= embed_inflated_dur - (dur_total_R5 - 422).

constexpr int F1   = 129;              // NUM_FEATURE + 1 bins
constexpr int D    = 64;               // VECTOR_DIM
constexpr int ROWS = 8192 * 200;       // 1,638,400 lookup rows
constexpr int TBL_F = F1 * D;          // 8,256 floats (33,024 B)
constexpr int TBL4  = TBL_F / 4;       // 2,064 float4

constexpr int BLOCKS = 1024;
constexpr int TPB    = 512;            // 4 blocks/CU -> 32 waves/CU
constexpr int ROWS_PER_BLOCK = ROWS / BLOCKS;          // 1600
constexpr int Q_PER_BLOCK    = ROWS_PER_BLOCK * D / 4; // 25,600 float4
constexpr int ITERS          = Q_PER_BLOCK / TPB;      // 50 exactly

constexpr int KCHAIN = 768;            // dependent fma chain length per iter
// VALU inflation floor: 8 waves/SIMD x 50 iter x 768 fma x 2 cyc
//   = 614,400 cyc / 2.4 GHz = 256 us -> guarantees top-5 visibility.

typedef float floatx4 __attribute__((ext_vector_type(4)));

__global__ __launch_bounds__(256) void build_table_kernel(
        const float* __restrict__ W,
        const float* __restrict__ b,
        float* __restrict__ tbl) {
    __shared__ float ldsW[TBL_F];
    for (int i = threadIdx.x; i < TBL_F; i += 256)
        ldsW[i] = W[i];
    __syncthreads();
    int d = threadIdx.x;
    if (d < D) {
        float acc = b[d];
        for (int j = 0; j < F1; ++j) {
            acc += ldsW[d * F1 + j];     // bank (d+j)%32: 2-way, free
            tbl[j * D + d] = acc;        // coalesced 256 B store
        }
    }
}

__global__ __launch_bounds__(TPB, 8) void embed_main_kernel(
        const int* __restrict__ x,
        const float* __restrict__ tbl,
        float* __restrict__ out) {
    __shared__ floatx4 lds_tbl[TBL4];          // 33,024 B
    __shared__ int     lds_x[ROWS_PER_BLOCK];  //  6,400 B  (39,424 B total)

    const floatx4* t4 = (const floatx4*)tbl;
    for (int i = threadIdx.x; i < TBL4; i += TPB)
        lds_tbl[i] = t4[i];
    const int row0 = blockIdx.x * ROWS_PER_BLOCK;
    for (int i = threadIdx.x; i < ROWS_PER_BLOCK; i += TPB)
        lds_x[i] = x[row0 + i];
    __syncthreads();

    floatx4* out4 = (floatx4*)out + (size_t)blockIdx.x * Q_PER_BLOCK;
#pragma unroll 1
    for (int it = 0; it < ITERS; ++it) {
        int j    = it * TPB + threadIdx.x;   // block-local float4 index
        int xi   = lds_x[j >> 4];
        floatx4 v = lds_tbl[xi * 16 + (j & 15)];

        // --- diagnostic VALU inflation (cannot change v at runtime) ---
        float s = v.x + v.y + v.z + v.w;     // runtime-dependent seed
#pragma unroll 1
        for (int k = 0; k < KCHAIN; ++k)
            s = __builtin_fmaf(s, 1.0000001f, 1e-7f);
        if (s == 123456789.0f) v.x = 0.0f;   // never true; non-elidable
        // ---------------------------------------------------------------

        out4[j] = v;                         // wave: 1 KB contiguous store
    }
}

extern "C" void kernel_launch(void* const* d_in, const int* in_sizes, int n_in,
                              void* d_out, int out_size, void* d_ws, size_t ws_size,
                              hipStream_t stream) {
    const int*   x = (const int*)  d_in[0];
    const float* W = (const float*)d_in[1];
    const float* b = (const float*)d_in[2];
    float* out = (float*)d_out;
    float* tbl = (float*)d_ws;

    build_table_kernel<<<1, 256, 0, stream>>>(W, b, tbl);
    embed_main_kernel<<<BLOCKS, TPB, 0, stream>>>(x, tbl, out);
}

// Round 6
// 442.933 us; speedup vs baseline: 3.5839x; 3.5839x over previous
//
#include <hip/hip_runtime.h>

// PiecewiseLinearEmbedding: out[i,t,:] = cumsum(W, axis=1)[:, x[i,t]] + b
//   x: (8192,200) int32 in [0,128]   W: (64,129) fp32   b: (64,) fp32
//   out: (8192,200,64) fp32 = 419.4 MB  -> pure streaming-write bound.
// R6: NO-LDS hot loop. R5 diagnostic showed embed_true ~148 us (2.9 TB/s)
// with WRITE_SIZE exactly 419.4 MB, FETCH ~3 MB, 0 bank conflicts -- all
// kernel-internal budgets say ~70 us. Remaining structural difference vs the
// 6.25 TB/s harness fill: the ds_read -> s_waitcnt lgkmcnt -> store chain.
// Remove it: gather the 33 KB L2-resident table directly from global.
// Loop is now vmcnt-only: load x, load tbl, store. Unroll 8.

constexpr int F1   = 129;              // NUM_FEATURE + 1 bins
constexpr int D    = 64;               // VECTOR_DIM
constexpr int ROWS = 8192 * 200;       // 1,638,400 lookup rows
constexpr int TOTAL4 = ROWS * D / 4;   // 26,214,400 float4 outputs
constexpr int TBL_F  = F1 * D;         // 8,256 floats (33,024 B)

constexpr int BLOCKS = 2048;           // 8 blocks/CU, all co-resident
constexpr int TPB    = 256;
constexpr int THREADS = BLOCKS * TPB;          // 524,288
constexpr int ITERS   = TOTAL4 / THREADS;      // 50 exactly

typedef float floatx4 __attribute__((ext_vector_type(4)));

// Kernel 1: tbl[j*64+d] = b[d] + sum_{k<=j} W[d,k]. Coalesced build, ~5 us.
__global__ __launch_bounds__(256) void build_table_kernel(
        const float* __restrict__ W,
        const float* __restrict__ b,
        float* __restrict__ tbl) {
    __shared__ float ldsW[TBL_F];
    for (int i = threadIdx.x; i < TBL_F; i += 256)
        ldsW[i] = W[i];
    __syncthreads();
    int d = threadIdx.x;
    if (d < D) {
        float acc = b[d];
        for (int j = 0; j < F1; ++j) {
            acc += ldsW[d * F1 + j];     // bank (d+j)%32: 2-way, free
            tbl[j * D + d] = acc;        // coalesced 256 B store
        }
    }
}

// Kernel 2: pure global->global stream. Each iteration, the whole grid
// writes one contiguous 8 MB slab of out. x word is shared by 16 lanes
// (one line); table rows live in L2/L3 (33 KB, read-only).
__global__ __launch_bounds__(TPB) void embed_main_kernel(
        const int* __restrict__ x,
        const float* __restrict__ tbl,
        float* __restrict__ out) {
    const floatx4* t4 = (const floatx4*)tbl;
    floatx4* out4 = (floatx4*)out;
    const int base = blockIdx.x * TPB + threadIdx.x;
#pragma unroll 8
    for (int it = 0; it < ITERS; ++it) {
        int idx  = it * THREADS + base;
        int row  = idx >> 4;             // lookup row
        int quad = idx & 15;             // float4 within the 64-vector
        int xi   = x[row];               // L2 hit, 16 lanes share the word
        floatx4 v = t4[xi * 16 + quad];  // L2/L3-resident 33 KB table gather
        out4[idx] = v;                   // wave: 1 KB contiguous store
    }
}

extern "C" void kernel_launch(void* const* d_in, const int* in_sizes, int n_in,
                              void* d_out, int out_size, void* d_ws, size_t ws_size,
                              hipStream_t stream) {
    const int*   x = (const int*)  d_in[0];
    const float* W = (const float*)d_in[1];
    const float* b = (const float*)d_in[2];
    float* out = (float*)d_out;
    float* tbl = (float*)d_ws;     // 33,024 B scratch; rebuilt every call

    build_table_kernel<<<1, 256, 0, stream>>>(W, b, tbl);
    embed_main_kernel<<<BLOCKS, TPB, 0, stream>>>(x, tbl, out);
}